// Round 11
// baseline (235.839 us; speedup 1.0000x reference)
//
#include <hip/hip_runtime.h>
#include <math.h>

#define B_    8
#define N_    1025
#define H_    12
#define HD_   64
#define C_    768
#define BH_   (B_*H_)
#define NTOK  (B_*N_)          // 8200
#define SCALE 0.125f
#define NPAD  1092             // bucketT row stride (mult of 4); table is SYMMETRIC: [a][b]=bucket(a,b)
#define NPADV 1088             // vt row stride (17*64)

#define QKV_ELEMS (BH_*N_*HD_)         // 6,297,600

// ws layout (bytes)
#define XB_OFF_B     ((size_t)0)
#define WQKV_OFF_B   (XB_OFF_B + (size_t)NTOK*C_*2)
#define WPROJ_OFF_B  (WQKV_OFF_B + (size_t)3*C_*C_*2)
#define QB_OFF_B     (WPROJ_OFF_B + (size_t)C_*C_*2)
#define KB_OFF_B     (QB_OFF_B + (size_t)QKV_ELEMS*2)
#define AOB_OFF_B    (KB_OFF_B + (size_t)QKV_ELEMS*2)
#define VT_OFF_B     (AOB_OFF_B + (size_t)QKV_ELEMS*2)
#define BUCKET_OFF_B (VT_OFF_B + (size_t)BH_*HD_*NPADV*2)

typedef __attribute__((ext_vector_type(8))) short s8bf;
typedef __attribute__((ext_vector_type(8))) unsigned short u8s;
typedef __attribute__((ext_vector_type(4))) float v4f;
typedef unsigned short ushort_t;

// async global -> LDS, 16B per lane. LDS dest must be wave-uniform base
// (HW writes base + lane*16); global src is per-lane.
#define GLOAD16(gp, lp) __builtin_amdgcn_global_load_lds( \
    (const __attribute__((address_space(1))) unsigned int*)(gp), \
    (__attribute__((address_space(3))) unsigned int*)(lp), 16, 0, 0)

// raw workgroup barrier with compiler memory fence (no vmcnt drain, unlike __syncthreads)
#define SBAR() do { \
    __builtin_amdgcn_sched_barrier(0); \
    asm volatile("s_barrier" ::: "memory"); \
    __builtin_amdgcn_sched_barrier(0); \
} while (0)
// pinned counted vmcnt (sched_barrier blocks motion across — rule 18/m152)
#define VMW(N) do { \
    __builtin_amdgcn_sched_barrier(0); \
    asm volatile("s_waitcnt vmcnt(" #N ")" ::: "memory"); \
    __builtin_amdgcn_sched_barrier(0); \
} while (0)

// hand-RNE f32->bf16 (KEEP for all persistent tensors: v_cvt_pk_bf16_f32 asm path
// failed absmax in R3 — rounding-mode bias accumulated coherently)
__device__ __forceinline__ unsigned short f2bf(float x) {
    union { float f; unsigned u; } v; v.f = x;
    unsigned r = v.u + 0x7FFFu + ((v.u >> 16) & 1u);
    return (unsigned short)(r >> 16);
}
// round-half-up pack of two NONNEGATIVE floats (P values): differs from RNE only on
// exact ties (measure-zero after exp; no coherent bias). 5 ops/pair vs ~11.
__device__ __forceinline__ unsigned packbf_hu(float lo, float hi) {
    union { float f; unsigned u; } a, b; a.f = lo; b.f = hi;
    return ((a.u + 0x8000u) >> 16) | ((b.u + 0x8000u) & 0xFFFF0000u);
}

// ---- bucketT[a][b] = bucket(a,b), integer-exact & SYMMETRIC: {d2=0:0, d2<=2:1, d2<=12:2, else 3}, cls:7 ----
__global__ void bucket_kernel(unsigned char* __restrict__ bucketT) {
    int tid = blockIdx.x * 256 + threadIdx.x;
    if (tid >= N_ * NPAD) return;
    unsigned ut = (unsigned)tid;
    int j = ut / (unsigned)NPAD, i = ut % (unsigned)NPAD;
    if (i >= N_) i = N_ - 1;
    int bk;
    if (i < 1 || j < 1) {
        bk = 7;
    } else {
        int pi = i - 1, pj = j - 1;
        int dy = (pi >> 5) - (pj >> 5);
        int dx = (pi & 31) - (pj & 31);
        int d2 = dy*dy + dx*dx;
        bk = (d2 == 0) ? 0 : ((d2 <= 2) ? 1 : ((d2 <= 12) ? 2 : 3));
    }
    bucketT[tid] = (unsigned char)bk;
}

// ---------------- fused f32 -> bf16 cast (x, qkv_w, proj_w) ----------------
__global__ __launch_bounds__(256) void cast_kernel(
        const float* __restrict__ x, const float* __restrict__ w1,
        const float* __restrict__ w2,
        ushort_t* __restrict__ xb, ushort_t* __restrict__ w1b,
        ushort_t* __restrict__ w2b) {
    const int NX = NTOK * C_ / 8, NW1 = 3 * C_ * C_ / 8, NW2 = C_ * C_ / 8;
    int g = blockIdx.x * 256 + threadIdx.x;
    const float* src; ushort_t* dst; int idx;
    if (g < NX)                 { src = x;  dst = xb;  idx = g; }
    else if (g < NX + NW1)      { src = w1; dst = w1b; idx = g - NX; }
    else if (g < NX + NW1 + NW2){ src = w2; dst = w2b; idx = g - NX - NW1; }
    else return;
    size_t off = (size_t)idx * 8;
    float4 a = *(const float4*)(src + off);
    float4 c = *(const float4*)(src + off + 4);
    __align__(16) ushort_t h[8] = {f2bf(a.x), f2bf(a.y), f2bf(a.z), f2bf(a.w),
                                   f2bf(c.x), f2bf(c.y), f2bf(c.z), f2bf(c.w)};
    *(u8s*)(dst + off) = *(u8s*)h;
}

// ---------------- bf16 MFMA GEMM: 128x128 tile, BK=64, DOUBLE-BUFFERED global_load_lds ----------------
// T1 XCD swizzle (bijective, m204): xcd=L%8 owns contiguous wg-range, c0-fastest.
__global__ __launch_bounds__(256) void qkv_kernel(
        const ushort_t* __restrict__ xb, const ushort_t* __restrict__ wb,
        ushort_t* __restrict__ qb, ushort_t* __restrict__ kb, ushort_t* __restrict__ vt) {
    __shared__ __align__(16) ushort_t As0[128*64];
    __shared__ __align__(16) ushort_t Bs0[128*64];
    __shared__ __align__(16) ushort_t As1[128*64];
    __shared__ __align__(16) ushort_t Bs1[128*64];
    // bijective XCD remap: nwg=1170, q=146, r=2
    const int L = blockIdx.x + blockIdx.y * 65;
    const int xcd = L & 7, idx = L >> 3;
    const int wg = (xcd < 2 ? xcd * 147 : 2 * 147 + (xcd - 2) * 146) + idx;
    const int m0 = (wg / 18) * 128, c0 = (wg % 18) * 128;
    const int t = threadIdx.x;
    const int w = t >> 6, lane = t & 63, lc = lane & 15, lq = lane >> 4;
    const int wm = (w >> 1) * 64, wn = (w & 1) * 64;
    const int srow8 = w * 32 + (lane >> 3);                    // + i*8 = row within tile
    const int gsw8  = (((lane & 7) ^ (lane >> 3)) & 7) * 8;    // swizzled source col (ushorts)

    v4f acc[4][4];
#pragma unroll
    for (int mt = 0; mt < 4; mt++)
#pragma unroll
        for (int nt = 0; nt < 4; nt++) acc[mt][nt] = (v4f){0.f, 0.f, 0.f, 0.f};

    auto STAGE = [&](ushort_t* Ad, ushort_t* Bd, int k0) {
#pragma unroll
        for (int i = 0; i < 4; i++) {
            int row = srow8 + i * 8;
            int m = m0 + row; if (m > NTOK - 1) m = NTOK - 1;   // clamp: dup reads, rows masked in epilogue
            GLOAD16(xb + (size_t)m * C_ + k0 + gsw8,           &Ad[(w*32 + i*8) * 64]);
            GLOAD16(wb + (size_t)(c0 + row) * C_ + k0 + gsw8,  &Bd[(w*32 + i*8) * 64]);
        }
    };
    auto COMPUTE = [&](const ushort_t* A, const ushort_t* B) {
#pragma unroll
        for (int kk = 0; kk < 64; kk += 32) {
            s8bf af[4], bf[4];
#pragma unroll
            for (int mt = 0; mt < 4; mt++)
                af[mt] = *(const s8bf*)&A[(wm + mt*16 + lc) * 64 + ((((kk>>3) + lq) ^ (lc & 7)) * 8)];
#pragma unroll
            for (int nt = 0; nt < 4; nt++)
                bf[nt] = *(const s8bf*)&B[(wn + nt*16 + lc) * 64 + ((((kk>>3) + lq) ^ (lc & 7)) * 8)];
#pragma unroll
            for (int mt = 0; mt < 4; mt++)
#pragma unroll
                for (int nt = 0; nt < 4; nt++)
                    acc[mt][nt] = __builtin_amdgcn_mfma_f32_16x16x32_bf16(af[mt], bf[nt], acc[mt][nt], 0, 0, 0);
        }
    };

    STAGE(As0, Bs0, 0);
#pragma unroll
    for (int it = 0; it < 6; ++it) {
        const int k0 = it * 128;
        if (k0 + 64 < C_) {
            STAGE(As1, Bs1, k0 + 64);
            asm volatile("s_waitcnt vmcnt(8)" ::: "memory");
        } else {
            asm volatile("s_waitcnt vmcnt(0)" ::: "memory");
        }
        SBAR();
        COMPUTE(As0, Bs0);
        SBAR();
        if (k0 + 128 < C_) {
            STAGE(As0, Bs0, k0 + 128);
            asm volatile("s_waitcnt vmcnt(8)" ::: "memory");
        } else {
            asm volatile("s_waitcnt vmcnt(0)" ::: "memory");
        }
        SBAR();
        COMPUTE(As1, Bs1);
        if (it < 5) SBAR();
    }

#pragma unroll
    for (int mt = 0; mt < 4; mt++) {
#pragma unroll
        for (int r = 0; r < 4; r++) {
            int m = m0 + wm + mt*16 + lq*4 + r;
            if (m >= NTOK) continue;
            unsigned um = (unsigned)m;
            int b = um / (unsigned)N_, n = um % (unsigned)N_;
#pragma unroll
            for (int nt = 0; nt < 4; nt++) {
                int c = c0 + wn + nt*16 + lc;
                int comp = c / C_, rem = c % C_;
                int h = rem >> 6, d0 = rem & 63;
                float val = acc[mt][nt][r] * ((comp == 0) ? SCALE : 1.0f);
                if (comp == 2) {
                    vt[((size_t)((b*H_ + h)*HD_ + d0))*NPADV + n] = f2bf(val);
                } else {
                    ushort_t* dst = (comp == 0) ? qb : kb;
                    dst[((size_t)((b*H_ + h)*N_ + n))*HD_ + d0] = f2bf(val);
                }
            }
        }
    }
}

// ---------------- attention: QBLK=128 (two 64-row Q-halves per block) ----------------
// R10's verified gload_lds pipeline (sigma-permuted source, vmcnt(4), raw SBARs) kept
// verbatim; Q doubled so grid = 96x9 = 864 blocks <= 1024 resident at 4 blocks/CU
// (fixes R10's 608-block tail round). Shared kf/vf LDS reads now feed 2x MFMA;
// per-output staging & K/V fetch halve.
#define LUTS 9

__global__ __launch_bounds__(256) void attn_kernel(
        const ushort_t* __restrict__ qb, const ushort_t* __restrict__ kb,
        const ushort_t* __restrict__ vt, const float* __restrict__ rpe,
        const unsigned char* __restrict__ bucketT, ushort_t* __restrict__ ao) {
    __shared__ __align__(16) ushort_t Ks0[64*64];
    __shared__ __align__(16) ushort_t Vs0[64*64];
    __shared__ __align__(16) ushort_t Ks1[64*64];   // prologue alias rows 0..15: rpe^T
    __shared__ __align__(16) ushort_t Vs1[64*64];   // prologue alias: Q halves
    __shared__ float lut[128*LUTS];                 // col 8: lsum broadcast (epilogue)

    const int bh = blockIdx.x, it0 = blockIdx.y;    // bh-major: all i-tiles of bh on one XCD
    const int b  = bh / H_, hh = bh % H_;
    const int i0 = it0 * 128;
    const int t  = threadIdx.x;
    const int w  = t >> 6, lane = t & 63, lc = lane & 15, lq = lane >> 4;
    const int row_w = w * 16;                       // wave strip (16 rows per half)
    const int rs = lc & 7;                          // read-swizzle key (all frag rows ≡ lc mod 8)
    const int gA = ((lq ^ rs) & 7) * 8;             // frag0 swizzled col (granule lq)
    const int gB = (((lq + 4) ^ rs) & 7) * 8;       // frag1 swizzled col (granule 4+lq)

    const ushort_t* qp = qb + (size_t)bh * N_ * HD_;
    const ushort_t* kp = kb + (size_t)bh * N_ * HD_;
    const ushort_t* vp = vt + (size_t)bh * HD_ * NPADV;

    // ---- stage Q half a into Vs1 (zero rows >= N), rpe^T into Ks1, addr-swizzled ----
    {
        int row = t >> 2, g0 = (t & 3) * 2, qrs = row & 7;
        int gi = i0 + row;
        u8s h0 = (u8s)0, h1 = (u8s)0;
        if (gi < N_) {
            h0 = *(const u8s*)(qp + (size_t)gi * HD_ + g0*8);
            h1 = *(const u8s*)(qp + (size_t)gi * HD_ + g0*8 + 8);
        }
        *(u8s*)&Vs1[row*64 + ((g0 ^ qrs) * 8)]       = h0;
        *(u8s*)&Vs1[row*64 + (((g0+1) ^ qrs) * 8)]   = h1;
    }
    if (t < 64) {
        float4 r0 = *(const float4*)(rpe + t*8);
        float4 r1 = *(const float4*)(rpe + t*8 + 4);
        const int gr = t >> 3, go = t & 7;
        float vals[8] = {r0.x, r0.y, r0.z, r0.w, r1.x, r1.y, r1.z, r1.w};
#pragma unroll
        for (int m = 0; m < 8; m++)
            Ks1[m*64 + ((gr ^ (m & 7)) * 8) + go] = f2bf(vals[m]);
    } else if (t < 128) {
        int idx = t - 64;
        int m = 8 + (idx >> 3), g = idx & 7;
        *(u8s*)&Ks1[m*64 + ((g ^ (m & 7)) * 8)] = (u8s)0;
    }
    __syncthreads();

    // ---- Q half-a fragments + rpe fragments; lut_a MFMA ----
    s8bf qfa0 = *(s8bf*)&Vs1[(row_w + lc)*64 + gA];
    s8bf qfa1 = *(s8bf*)&Vs1[(row_w + lc)*64 + gB];
    s8bf rf0 = *(s8bf*)&Ks1[lc*64 + gA];
    s8bf rf1 = *(s8bf*)&Ks1[lc*64 + gB];
    v4f la_a = (v4f){0.f, 0.f, 0.f, 0.f};
    la_a = __builtin_amdgcn_mfma_f32_16x16x32_bf16(qfa0, rf0, la_a, 0, 0, 0);
    la_a = __builtin_amdgcn_mfma_f32_16x16x32_bf16(qfa1, rf1, la_a, 0, 0, 0);
    __syncthreads();   // all waves' Qa reads retired (consumed by lut_a MFMA) before overwrite

    // ---- stage Q half b into Vs1 ----
    {
        int row = t >> 2, g0 = (t & 3) * 2, qrs = row & 7;
        int gi = i0 + 64 + row;
        u8s h0 = (u8s)0, h1 = (u8s)0;
        if (gi < N_) {
            h0 = *(const u8s*)(qp + (size_t)gi * HD_ + g0*8);
            h1 = *(const u8s*)(qp + (size_t)gi * HD_ + g0*8 + 8);
        }
        *(u8s*)&Vs1[row*64 + ((g0 ^ qrs) * 8)]       = h0;
        *(u8s*)&Vs1[row*64 + (((g0+1) ^ qrs) * 8)]   = h1;
    }
    __syncthreads();
    s8bf qfb0 = *(s8bf*)&Vs1[(row_w + lc)*64 + gA];
    s8bf qfb1 = *(s8bf*)&Vs1[(row_w + lc)*64 + gB];
    v4f la_b = (v4f){0.f, 0.f, 0.f, 0.f};
    la_b = __builtin_amdgcn_mfma_f32_16x16x32_bf16(qfb0, rf0, la_b, 0, 0, 0);
    la_b = __builtin_amdgcn_mfma_f32_16x16x32_bf16(qfb1, rf1, la_b, 0, 0, 0);
    if (lc < 8) {
#pragma unroll
        for (int r = 0; r < 4; r++) {
            lut[(row_w + lq*4 + r)*LUTS + lc]        = la_a[r];
            lut[(64 + row_w + lq*4 + r)*LUTS + lc]   = la_b[r];
        }
    }

    int myrow_a = i0 + row_w + lc;       if (myrow_a > N_ - 1) myrow_a = N_ - 1;
    int myrow_b = i0 + 64 + row_w + lc;  if (myrow_b > N_ - 1) myrow_b = N_ - 1;
    const unsigned char* bkrow_a = bucketT + (size_t)myrow_a * NPAD;
    const unsigned char* bkrow_b = bucketT + (size_t)myrow_b * NPAD;
    const int lutbase_a = (row_w + lc) * LUTS;
    const int lutbase_b = (64 + row_w + lc) * LUTS;
    // per-lane j base within tile for quadrant t4: 32*(t4>>1) + 4*(t4&1) + 8*lq
    const int jb0 = 8*lq, jb1 = 8*lq + 4, jb2 = 8*lq + 32, jb3 = 8*lq + 36;
    unsigned bka[4], bkb[4];

    // ---- STAGE via global_load_lds (R10-verified): linear dest, sigma+XOR pre-permuted source ----
    auto STAGEA = [&](ushort_t* Kd, ushort_t* Vd, int jbase) {
#pragma unroll
        for (int i = 0; i < 2; i++) {
            int s = w*16 + i*8 + (lane >> 3);
            int jr = 32*(s>>5) + 8*((s>>2)&3) + 4*((s>>4)&1) + (s&3);
            int gj = jbase + jr; if (gj > N_ - 1) gj = N_ - 1;
            GLOAD16(kp + (size_t)gj * HD_ + (((lane&7) ^ (s&7)) * 8), &Kd[(w*16 + i*8)*64]);
        }
#pragma unroll
        for (int i = 0; i < 2; i++) {
            int d = w*16 + i*8 + (lane >> 3);
            GLOAD16(vp + (size_t)d * NPADV + jbase + (((lane&7) ^ (d&7)) * 8), &Vd[(w*16 + i*8)*64]);
        }
    };

    v4f oa[4], ob[4];
    float lsa = 0.f, lsb = 0.f;
#pragma unroll
    for (int dt = 0; dt < 4; dt++) { oa[dt] = (v4f){0.f,0.f,0.f,0.f}; ob[dt] = (v4f){0.f,0.f,0.f,0.f}; }

    // ---- one tile: shared kf/vf reads feed both Q-halves ----
    auto TILE = [&](const ushort_t* Kb, const ushort_t* Vb, int nextj, bool tail) {
        v4f aa[4], ab[4];
#pragma unroll
        for (int t4 = 0; t4 < 4; t4++) { aa[t4] = (v4f){0.f,0.f,0.f,0.f}; ab[t4] = (v4f){0.f,0.f,0.f,0.f}; }
#pragma unroll
        for (int t4 = 0; t4 < 4; t4++) {
            s8bf kf0 = *(const s8bf*)&Kb[(t4*16 + lc)*64 + gA];
            s8bf kf1 = *(const s8bf*)&Kb[(t4*16 + lc)*64 + gB];
            aa[t4] = __builtin_amdgcn_mfma_f32_16x16x32_bf16(kf0, qfa0, aa[t4], 0, 0, 0);
            aa[t4] = __builtin_amdgcn_mfma_f32_16x16x32_bf16(kf1, qfa1, aa[t4], 0, 0, 0);
            ab[t4] = __builtin_amdgcn_mfma_f32_16x16x32_bf16(kf0, qfb0, ab[t4], 0, 0, 0);
            ab[t4] = __builtin_amdgcn_mfma_f32_16x16x32_bf16(kf1, qfb1, ab[t4], 0, 0, 0);
        }
        unsigned pwa[8], pwb[8];
        if (!tail) {
#pragma unroll
            for (int t4 = 0; t4 < 4; t4++) {
                int k0b = (bka[t4]      ) & 0xFF; float p0 = __expf(aa[t4][0] + lut[lutbase_a + k0b]);
                int k1b = (bka[t4] >>  8) & 0xFF; float p1 = __expf(aa[t4][1] + lut[lutbase_a + k1b]);
                int k2b = (bka[t4] >> 16) & 0xFF; float p2 = __expf(aa[t4][2] + lut[lutbase_a + k2b]);
                int k3b = (bka[t4] >> 24)       ; float p3 = __expf(aa[t4][3] + lut[lutbase_a + k3b]);
                lsa += (p0 + p1) + (p2 + p3);
                pwa[t4*2]     = packbf_hu(p0, p1);
                pwa[t4*2 + 1] = packbf_hu(p2, p3);
            }
#pragma unroll
            for (int t4 = 0; t4 < 4; t4++) {
                int k0b = (bkb[t4]      ) & 0xFF; float p0 = __expf(ab[t4][0] + lut[lutbase_b + k0b]);
                int k1b = (bkb[t4] >>  8) & 0xFF; float p1 = __expf(ab[t4][1] + lut[lutbase_b + k1b]);
                int k2b = (bkb[t4] >> 16) & 0xFF; float p2 = __expf(ab[t4][2] + lut[lutbase_b + k2b]);
                int k3b = (bkb[t4] >> 24)       ; float p3 = __expf(ab[t4][3] + lut[lutbase_b + k3b]);
                lsb += (p0 + p1) + (p2 + p3);
                pwb[t4*2]     = packbf_hu(p0, p1);
                pwb[t4*2 + 1] = packbf_hu(p2, p3);
            }
        } else {
            const int jbs[4] = {jb0, jb1, jb2, jb3};
#pragma unroll
            for (int t4 = 0; t4 < 4; t4++) {
                float pva[4], pvb[4];
#pragma unroll
                for (int r = 0; r < 4; r++) {
                    bool jv = (jbs[t4] + r) == 0;   // only j==1024 valid
                    int bk_a = (bka[t4] >> (8*r)) & 0xFF;
                    float pa = __expf(aa[t4][r] + lut[lutbase_a + bk_a]);
                    if (!jv) pa = 0.f;
                    lsa += pa; pva[r] = pa;
                    int bk_b = (bkb[t4] >> (8*r)) & 0xFF;
                    float pb2 = __expf(ab[t4][r] + lut[lutbase_b + bk_b]);
                    if (!jv) pb2 = 0.f;
                    lsb += pb2; pvb[r] = pb2;
                }
                pwa[t4*2] = packbf_hu(pva[0], pva[1]); pwa[t4*2+1] = packbf_hu(pva[2], pva[3]);
                pwb[t4*2] = packbf_hu(pvb[0], pvb[1]); pwb[t4*2+1] = packbf_hu(pvb[2], pvb[3]);
            }
        }
        if (nextj >= 0) {   // issue next tile's bucket loads AFTER softmax consumed bk
            bka[0] = *(const unsigned*)(bkrow_a + nextj + jb0);
            bka[1] = *(const unsigned*)(bkrow_a + nextj + jb1);
            bka[2] = *(const unsigned*)(bkrow_a + nextj + jb2);
            bka[3] = *(const unsigned*)(bkrow_a + nextj + jb3);
            bkb[0] = *(const unsigned*)(bkrow_b + nextj + jb0);
            bkb[1] = *(const unsigned*)(bkrow_b + nextj + jb1);
            bkb[2] = *(const unsigned*)(bkrow_b + nextj + jb2);
            bkb[3] = *(const unsigned*)(bkrow_b + nextj + jb3);
        }
        s8bf pfa0 = *(s8bf*)&pwa[0];
        s8bf pfa1 = *(s8bf*)&pwa[4];
        s8bf pfb0 = *(s8bf*)&pwb[0];
        s8bf pfb1 = *(s8bf*)&pwb[4];
#pragma unroll
        for (int dt = 0; dt < 4; dt++) {
            s8bf vf0 = *(const s8bf*)&Vb[(dt*16 + lc)*64 + gA];
            s8bf vf1 = *(const s8bf*)&Vb[(dt*16 + lc)*64 + gB];
            oa[dt] = __builtin_amdgcn_mfma_f32_16x16x32_bf16(pfa0, vf0, oa[dt], 0, 0, 0);
            oa[dt] = __builtin_amdgcn_mfma_f32_16x16x32_bf16(pfa1, vf1, oa[dt], 0, 0, 0);
            ob[dt] = __builtin_amdgcn_mfma_f32_16x16x32_bf16(pfb0, vf0, ob[dt], 0, 0, 0);
            ob[dt] = __builtin_amdgcn_mfma_f32_16x16x32_bf16(pfb1, vf1, ob[dt], 0, 0, 0);
        }
    };

    // ---- pipeline prologue: stage tile0 -> buf0; bucket(0) ----
    STAGEA(Ks0, Vs0, 0);
    bka[0] = *(const unsigned*)(bkrow_a + jb0);
    bka[1] = *(const unsigned*)(bkrow_a + jb1);
    bka[2] = *(const unsigned*)(bkrow_a + jb2);
    bka[3] = *(const unsigned*)(bkrow_a + jb3);
    bkb[0] = *(const unsigned*)(bkrow_b + jb0);
    bkb[1] = *(const unsigned*)(bkrow_b + jb1);
    bkb[2] = *(const unsigned*)(bkrow_b + jb2);
    bkb[3] = *(const unsigned*)(bkrow_b + jb3);
    SBAR();   // all waves done reading Ks1/Vs1 (Q/rpe frags) before loop overwrites buf1

    for (int it = 0; it < 8; ++it) {
        const int j0 = it * 128;
        // phase A: compute tile 2it (buf0), stage tile 2it+1 -> buf1
        STAGEA(Ks1, Vs1, j0 + 64);
        VMW(4);            // FIFO [cur 4, bk 8, next 4] -> leaves next's 4 in flight
        SBAR();
        TILE(Ks0, Vs0, j0 + 64, false);
        SBAR();
        // phase B: compute tile 2it+1 (buf1), stage tile 2it+2 -> buf0
        STAGEA(Ks0, Vs0, j0 + 128);
        VMW(4);
        SBAR();
        TILE(Ks1, Vs1, j0 + 128, false);
        SBAR();
    }
    // peel tile 16 (staged into buf0 at it=7 phase B; bk = bucket(1024))
    VMW(0);
    SBAR();
    TILE(Ks0, Vs0, -1, true);

    // ---- epilogue: reduce lsums over lq, bcast via lut col 8, store both halves ----
    lsa += __shfl_xor(lsa, 16);
    lsa += __shfl_xor(lsa, 32);
    lsb += __shfl_xor(lsb, 16);
    lsb += __shfl_xor(lsb, 32);
    if (lq == 0) {
        lut[(row_w + lc)*LUTS + 8]      = lsa;
        lut[(64 + row_w + lc)*LUTS + 8] = lsb;
    }
    __builtin_amdgcn_s_waitcnt(0);          // lgkm drain before same-wave read (wave-private rows)
#pragma unroll
    for (int r = 0; r < 4; r++) {
        int i = i0 + row_w + lq*4 + r;
        if (i < N_) {
            float inv = 1.0f / lut[(row_w + lq*4 + r)*LUTS + 8];
#pragma unroll
            for (int dt = 0; dt < 4; dt++)
                ao[((size_t)(b*N_ + i))*C_ + hh*HD_ + dt*16 + lc] = f2bf(oa[dt][r] * inv);
        }
        int i2 = i0 + 64 + row_w + lq*4 + r;
        if (i2 < N_) {
            float inv = 1.0f / lut[(64 + row_w + lq*4 + r)*LUTS + 8];
#pragma unroll
            for (int dt = 0; dt < 4; dt++)
                ao[((size_t)(b*N_ + i2))*C_ + hh*HD_ + dt*16 + lc] = f2bf(ob[dt][r] * inv);
        }
    }
}

// ---------------- proj: out(8200x768) = aob @ wprojb^T + bias, f32 out ----------------
// same T3+T4 pipeline + T1 bijective XCD swizzle (nwg=390: q=48, r=6)
__global__ __launch_bounds__(256) void proj_kernel(
        const ushort_t* __restrict__ ab, const ushort_t* __restrict__ wb,
        const float* __restrict__ bias, float* __restrict__ out) {
    __shared__ __align__(16) ushort_t As0[128*64];
    __shared__ __align__(16) ushort_t Bs0[128*64];
    __shared__ __align__(16) ushort_t As1[128*64];
    __shared__ __align__(16) ushort_t Bs1[128*64];
    const int L = blockIdx.x + blockIdx.y * 65;
    const int xcd = L & 7, idx = L >> 3;
    const int wg = (xcd < 6 ? xcd * 49 : 6 * 49 + (xcd - 6) * 48) + idx;
    const int m0 = (wg / 6) * 128, c0 = (wg % 6) * 128;
    const int t = threadIdx.x;
    const int w = t >> 6, lane = t & 63, lc = lane & 15, lq = lane >> 4;
    const int wm = (w >> 1) * 64, wn = (w & 1) * 64;
    const int srow8 = w * 32 + (lane >> 3);
    const int gsw8  = (((lane & 7) ^ (lane >> 3)) & 7) * 8;

    v4f acc[4][4];
#pragma unroll
    for (int mt = 0; mt < 4; mt++)
#pragma unroll
        for (int nt = 0; nt < 4; nt++) acc[mt][nt] = (v4f){0.f, 0.f, 0.f, 0.f};

    auto STAGE = [&](ushort_t* Ad, ushort_t* Bd, int k0) {
#pragma unroll
        for (int i = 0; i < 4; i++) {
            int row = srow8 + i * 8;
            int m = m0 + row; if (m > NTOK - 1) m = NTOK - 1;
            GLOAD16(ab + (size_t)m * C_ + k0 + gsw8,           &Ad[(w*32 + i*8) * 64]);
            GLOAD16(wb + (size_t)(c0 + row) * C_ + k0 + gsw8,  &Bd[(w*32 + i*8) * 64]);
        }
    };
    auto COMPUTE = [&](const ushort_t* A, const ushort_t* B) {
#pragma unroll
        for (int kk = 0; kk < 64; kk += 32) {
            s8bf af[4], bf[4];
#pragma unroll
            for (int mt = 0; mt < 4; mt++)
                af[mt] = *(const s8bf*)&A[(wm + mt*16 + lc) * 64 + ((((kk>>3) + lq) ^ (lc & 7)) * 8)];
#pragma unroll
            for (int nt = 0; nt < 4; nt++)
                bf[nt] = *(const s8bf*)&B[(wn + nt*16 + lc) * 64 + ((((kk>>3) + lq) ^ (lc & 7)) * 8)];
#pragma unroll
            for (int mt = 0; mt < 4; mt++)
#pragma unroll
                for (int nt = 0; nt < 4; nt++)
                    acc[mt][nt] = __builtin_amdgcn_mfma_f32_16x16x32_bf16(af[mt], bf[nt], acc[mt][nt], 0, 0, 0);
        }
    };

    STAGE(As0, Bs0, 0);
#pragma unroll
    for (int it = 0; it < 6; ++it) {
        const int k0 = it * 128;
        if (k0 + 64 < C_) {
            STAGE(As1, Bs1, k0 + 64);
            asm volatile("s_waitcnt vmcnt(8)" ::: "memory");
        } else {
            asm volatile("s_waitcnt vmcnt(0)" ::: "memory");
        }
        SBAR();
        COMPUTE(As0, Bs0);
        SBAR();
        if (k0 + 128 < C_) {
            STAGE(As0, Bs0, k0 + 128);
            asm volatile("s_waitcnt vmcnt(8)" ::: "memory");
        } else {
            asm volatile("s_waitcnt vmcnt(0)" ::: "memory");
        }
        SBAR();
        COMPUTE(As1, Bs1);
        if (it < 5) SBAR();
    }

    float pb[4];
#pragma unroll
    for (int nt = 0; nt < 4; nt++) pb[nt] = bias[c0 + wn + nt*16 + lc];
#pragma unroll
    for (int mt = 0; mt < 4; mt++) {
#pragma unroll
        for (int r = 0; r < 4; r++) {
            int m = m0 + wm + mt*16 + lq*4 + r;
            if (m >= NTOK) continue;
#pragma unroll
            for (int nt = 0; nt < 4; nt++) {
                int c = c0 + wn + nt*16 + lc;
                out[(size_t)m * C_ + c] = acc[mt][nt][r] + pb[nt];
            }
        }
    }
}

extern "C" void kernel_launch(void* const* d_in, const int* in_sizes, int n_in,
                              void* d_out, int out_size, void* d_ws, size_t ws_size,
                              hipStream_t stream) {
    const float* x      = (const float*)d_in[0];
    const float* qkv_w  = (const float*)d_in[1];
    const float* proj_w = (const float*)d_in[2];
    const float* proj_b = (const float*)d_in[3];
    const float* rpe_w  = (const float*)d_in[4];
    float* out = (float*)d_out;

    char* ws = (char*)d_ws;
    ushort_t* xb   = (ushort_t*)(ws + XB_OFF_B);
    ushort_t* wqkv = (ushort_t*)(ws + WQKV_OFF_B);
    ushort_t* wprj = (ushort_t*)(ws + WPROJ_OFF_B);
    ushort_t* qb   = (ushort_t*)(ws + QB_OFF_B);
    ushort_t* kb   = (ushort_t*)(ws + KB_OFF_B);
    ushort_t* aob  = (ushort_t*)(ws + AOB_OFF_B);
    ushort_t* vt   = (ushort_t*)(ws + VT_OFF_B);
    unsigned char* bucketT = (unsigned char*)(ws + BUCKET_OFF_B);

    const int ncast = (NTOK*C_ + 3*C_*C_ + C_*C_) / 8;
    bucket_kernel<<<dim3((N_*NPAD + 255)/256), 256, 0, stream>>>(bucketT);
    cast_kernel<<<dim3((ncast + 255)/256), 256, 0, stream>>>(x, qkv_w, proj_w, xb, wqkv, wprj);
    qkv_kernel<<<dim3(65, 18), 256, 0, stream>>>(xb, wqkv, qb, kb, vt);
    attn_kernel<<<dim3(96, 9), 256, 0, stream>>>(qb, kb, vt, rpe_w, bucketT, aob);
    proj_kernel<<<dim3(65, 6), 256, 0, stream>>>(aob, wprj, proj_b, out);
}

// Round 12
// 227.722 us; speedup vs baseline: 1.0356x; 1.0356x over previous
//
#include <hip/hip_runtime.h>
#include <math.h>

#define B_    8
#define N_    1025
#define H_    12
#define HD_   64
#define C_    768
#define BH_   (B_*H_)
#define NTOK  (B_*N_)          // 8200
#define SCALE 0.125f
#define NPAD  1092             // bucketT row stride (mult of 4); table is SYMMETRIC: [a][b]=bucket(a,b)
#define NPADV 1088             // vt row stride (17*64)

#define QKV_ELEMS (BH_*N_*HD_)         // 6,297,600

// ws layout (bytes)
#define XB_OFF_B     ((size_t)0)
#define WQKV_OFF_B   (XB_OFF_B + (size_t)NTOK*C_*2)
#define WPROJ_OFF_B  (WQKV_OFF_B + (size_t)3*C_*C_*2)
#define QB_OFF_B     (WPROJ_OFF_B + (size_t)C_*C_*2)
#define KB_OFF_B     (QB_OFF_B + (size_t)QKV_ELEMS*2)
#define AOB_OFF_B    (KB_OFF_B + (size_t)QKV_ELEMS*2)
#define VT_OFF_B     (AOB_OFF_B + (size_t)QKV_ELEMS*2)
#define BUCKET_OFF_B (VT_OFF_B + (size_t)BH_*HD_*NPADV*2)

typedef __attribute__((ext_vector_type(8))) short s8bf;
typedef __attribute__((ext_vector_type(8))) unsigned short u8s;
typedef __attribute__((ext_vector_type(4))) float v4f;
typedef unsigned short ushort_t;

// async global -> LDS, 16B per lane. LDS dest must be wave-uniform base
// (HW writes base + lane*16); global src is per-lane.
#define GLOAD16(gp, lp) __builtin_amdgcn_global_load_lds( \
    (const __attribute__((address_space(1))) unsigned int*)(gp), \
    (__attribute__((address_space(3))) unsigned int*)(lp), 16, 0, 0)

// raw workgroup barrier with compiler memory fence (no vmcnt drain, unlike __syncthreads)
#define SBAR() do { \
    __builtin_amdgcn_sched_barrier(0); \
    asm volatile("s_barrier" ::: "memory"); \
    __builtin_amdgcn_sched_barrier(0); \
} while (0)
// pinned counted vmcnt (sched_barrier blocks motion across — rule 18/m152)
#define VMW(N) do { \
    __builtin_amdgcn_sched_barrier(0); \
    asm volatile("s_waitcnt vmcnt(" #N ")" ::: "memory"); \
    __builtin_amdgcn_sched_barrier(0); \
} while (0)

// hand-RNE f32->bf16 (KEEP for all persistent tensors: v_cvt_pk_bf16_f32 asm path
// failed absmax in R3 — rounding-mode bias accumulated coherently)
__device__ __forceinline__ unsigned short f2bf(float x) {
    union { float f; unsigned u; } v; v.f = x;
    unsigned r = v.u + 0x7FFFu + ((v.u >> 16) & 1u);
    return (unsigned short)(r >> 16);
}
// round-half-up pack of two NONNEGATIVE floats (P values): differs from RNE only on
// exact ties (measure-zero after exp; no coherent bias). 5 ops/pair vs ~11.
__device__ __forceinline__ unsigned packbf_hu(float lo, float hi) {
    union { float f; unsigned u; } a, b; a.f = lo; b.f = hi;
    return ((a.u + 0x8000u) >> 16) | ((b.u + 0x8000u) & 0xFFFF0000u);
}

// ---- bucketT[a][b] = bucket(a,b), integer-exact & SYMMETRIC: {d2=0:0, d2<=2:1, d2<=12:2, else 3}, cls:7 ----
__global__ void bucket_kernel(unsigned char* __restrict__ bucketT) {
    int tid = blockIdx.x * 256 + threadIdx.x;
    if (tid >= N_ * NPAD) return;
    unsigned ut = (unsigned)tid;
    int j = ut / (unsigned)NPAD, i = ut % (unsigned)NPAD;
    if (i >= N_) i = N_ - 1;
    int bk;
    if (i < 1 || j < 1) {
        bk = 7;
    } else {
        int pi = i - 1, pj = j - 1;
        int dy = (pi >> 5) - (pj >> 5);
        int dx = (pi & 31) - (pj & 31);
        int d2 = dy*dy + dx*dx;
        bk = (d2 == 0) ? 0 : ((d2 <= 2) ? 1 : ((d2 <= 12) ? 2 : 3));
    }
    bucketT[tid] = (unsigned char)bk;
}

// ---------------- fused f32 -> bf16 cast (x, qkv_w, proj_w) ----------------
__global__ __launch_bounds__(256) void cast_kernel(
        const float* __restrict__ x, const float* __restrict__ w1,
        const float* __restrict__ w2,
        ushort_t* __restrict__ xb, ushort_t* __restrict__ w1b,
        ushort_t* __restrict__ w2b) {
    const int NX = NTOK * C_ / 8, NW1 = 3 * C_ * C_ / 8, NW2 = C_ * C_ / 8;
    int g = blockIdx.x * 256 + threadIdx.x;
    const float* src; ushort_t* dst; int idx;
    if (g < NX)                 { src = x;  dst = xb;  idx = g; }
    else if (g < NX + NW1)      { src = w1; dst = w1b; idx = g - NX; }
    else if (g < NX + NW1 + NW2){ src = w2; dst = w2b; idx = g - NX - NW1; }
    else return;
    size_t off = (size_t)idx * 8;
    float4 a = *(const float4*)(src + off);
    float4 c = *(const float4*)(src + off + 4);
    __align__(16) ushort_t h[8] = {f2bf(a.x), f2bf(a.y), f2bf(a.z), f2bf(a.w),
                                   f2bf(c.x), f2bf(c.y), f2bf(c.z), f2bf(c.w)};
    *(u8s*)(dst + off) = *(u8s*)h;
}

// ---------------- bf16 MFMA GEMM: 128x128 tile, BK=64, DOUBLE-BUFFERED global_load_lds ----------------
// T1 XCD swizzle (bijective, m204): xcd=L%8 owns contiguous wg-range, c0-fastest.
__global__ __launch_bounds__(256) void qkv_kernel(
        const ushort_t* __restrict__ xb, const ushort_t* __restrict__ wb,
        ushort_t* __restrict__ qb, ushort_t* __restrict__ kb, ushort_t* __restrict__ vt) {
    __shared__ __align__(16) ushort_t As0[128*64];
    __shared__ __align__(16) ushort_t Bs0[128*64];
    __shared__ __align__(16) ushort_t As1[128*64];
    __shared__ __align__(16) ushort_t Bs1[128*64];
    // bijective XCD remap: nwg=1170, q=146, r=2
    const int L = blockIdx.x + blockIdx.y * 65;
    const int xcd = L & 7, idx = L >> 3;
    const int wg = (xcd < 2 ? xcd * 147 : 2 * 147 + (xcd - 2) * 146) + idx;
    const int m0 = (wg / 18) * 128, c0 = (wg % 18) * 128;
    const int t = threadIdx.x;
    const int w = t >> 6, lane = t & 63, lc = lane & 15, lq = lane >> 4;
    const int wm = (w >> 1) * 64, wn = (w & 1) * 64;
    const int srow8 = w * 32 + (lane >> 3);                    // + i*8 = row within tile
    const int gsw8  = (((lane & 7) ^ (lane >> 3)) & 7) * 8;    // swizzled source col (ushorts)

    v4f acc[4][4];
#pragma unroll
    for (int mt = 0; mt < 4; mt++)
#pragma unroll
        for (int nt = 0; nt < 4; nt++) acc[mt][nt] = (v4f){0.f, 0.f, 0.f, 0.f};

    auto STAGE = [&](ushort_t* Ad, ushort_t* Bd, int k0) {
#pragma unroll
        for (int i = 0; i < 4; i++) {
            int row = srow8 + i * 8;
            int m = m0 + row; if (m > NTOK - 1) m = NTOK - 1;   // clamp: dup reads, rows masked in epilogue
            GLOAD16(xb + (size_t)m * C_ + k0 + gsw8,           &Ad[(w*32 + i*8) * 64]);
            GLOAD16(wb + (size_t)(c0 + row) * C_ + k0 + gsw8,  &Bd[(w*32 + i*8) * 64]);
        }
    };
    auto COMPUTE = [&](const ushort_t* A, const ushort_t* B) {
#pragma unroll
        for (int kk = 0; kk < 64; kk += 32) {
            s8bf af[4], bf[4];
#pragma unroll
            for (int mt = 0; mt < 4; mt++)
                af[mt] = *(const s8bf*)&A[(wm + mt*16 + lc) * 64 + ((((kk>>3) + lq) ^ (lc & 7)) * 8)];
#pragma unroll
            for (int nt = 0; nt < 4; nt++)
                bf[nt] = *(const s8bf*)&B[(wn + nt*16 + lc) * 64 + ((((kk>>3) + lq) ^ (lc & 7)) * 8)];
#pragma unroll
            for (int mt = 0; mt < 4; mt++)
#pragma unroll
                for (int nt = 0; nt < 4; nt++)
                    acc[mt][nt] = __builtin_amdgcn_mfma_f32_16x16x32_bf16(af[mt], bf[nt], acc[mt][nt], 0, 0, 0);
        }
    };

    STAGE(As0, Bs0, 0);
#pragma unroll
    for (int it = 0; it < 6; ++it) {
        const int k0 = it * 128;
        if (k0 + 64 < C_) {
            STAGE(As1, Bs1, k0 + 64);
            asm volatile("s_waitcnt vmcnt(8)" ::: "memory");
        } else {
            asm volatile("s_waitcnt vmcnt(0)" ::: "memory");
        }
        SBAR();
        COMPUTE(As0, Bs0);
        SBAR();
        if (k0 + 128 < C_) {
            STAGE(As0, Bs0, k0 + 128);
            asm volatile("s_waitcnt vmcnt(8)" ::: "memory");
        } else {
            asm volatile("s_waitcnt vmcnt(0)" ::: "memory");
        }
        SBAR();
        COMPUTE(As1, Bs1);
        if (it < 5) SBAR();
    }

#pragma unroll
    for (int mt = 0; mt < 4; mt++) {
#pragma unroll
        for (int r = 0; r < 4; r++) {
            int m = m0 + wm + mt*16 + lq*4 + r;
            if (m >= NTOK) continue;
            unsigned um = (unsigned)m;
            int b = um / (unsigned)N_, n = um % (unsigned)N_;
#pragma unroll
            for (int nt = 0; nt < 4; nt++) {
                int c = c0 + wn + nt*16 + lc;
                int comp = c / C_, rem = c % C_;
                int h = rem >> 6, d0 = rem & 63;
                float val = acc[mt][nt][r] * ((comp == 0) ? SCALE : 1.0f);
                if (comp == 2) {
                    vt[((size_t)((b*H_ + h)*HD_ + d0))*NPADV + n] = f2bf(val);
                } else {
                    ushort_t* dst = (comp == 0) ? qb : kb;
                    dst[((size_t)((b*H_ + h)*N_ + n))*HD_ + d0] = f2bf(val);
                }
            }
        }
    }
}

// ---------------- attention: R9 shape (QBLK=64, 8 blocks/CU, single round) ----------------
// + gload_lds single-buffer staging (R10's proven sigma+XOR pre-permuted SOURCE, linear dest).
// Removes R9's reg-staging VALU (~40-50 ops/tile) at ZERO LDS cost; the per-tile vmcnt(0)
// drain is TLP-hidden at 32 waves/CU (m97-vs-m151). R11 lesson: occupancy (8 blocks/CU,
// all 1632 blocks resident) is the binding constraint — don't trade it away.
#define LUTS 9

__global__ __launch_bounds__(256) void attn_kernel(
        const ushort_t* __restrict__ qb, const ushort_t* __restrict__ kb,
        const ushort_t* __restrict__ vt, const float* __restrict__ rpe,
        const unsigned char* __restrict__ bucketT, ushort_t* __restrict__ ao) {
    __shared__ __align__(16) ushort_t Ks[64*64];    // prologue alias rows 0..15: rpe^T
    __shared__ __align__(16) ushort_t Vs[64*64];    // prologue alias: Q tile
    __shared__ float lut[64*LUTS];                  // col 8: lsum broadcast (epilogue)

    const int bh = blockIdx.x, it0 = blockIdx.y;    // bh-major: all i-tiles of bh on one XCD
    const int b  = bh / H_, hh = bh % H_;
    const int i0 = it0 * 64;
    const int t  = threadIdx.x;
    const int w  = t >> 6, lane = t & 63, lc = lane & 15, lq = lane >> 4;
    const int row_w = w * 16;                       // wave strip (16 rows)
    const int rs = lc & 7;                          // read-swizzle key (all frag rows ≡ lc mod 8)
    const int gA = ((lq ^ rs) & 7) * 8;             // frag0 swizzled col (granule lq)
    const int gB = (((lq + 4) ^ rs) & 7) * 8;       // frag1 swizzled col (granule 4+lq)

    const ushort_t* qp = qb + (size_t)bh * N_ * HD_;
    const ushort_t* kp = kb + (size_t)bh * N_ * HD_;
    const ushort_t* vp = vt + (size_t)bh * HD_ * NPADV;

    // ---- stage Q into Vs (zero rows >= N), addr-swizzled ----
    {
        int row = t >> 2, g0 = (t & 3) * 2, qrs = row & 7;
        int gi = i0 + row;
        u8s h0 = (u8s)0, h1 = (u8s)0;
        if (gi < N_) {
            h0 = *(const u8s*)(qp + (size_t)gi * HD_ + g0*8);
            h1 = *(const u8s*)(qp + (size_t)gi * HD_ + g0*8 + 8);
        }
        *(u8s*)&Vs[row*64 + ((g0 ^ qrs) * 8)]       = h0;
        *(u8s*)&Vs[row*64 + (((g0+1) ^ qrs) * 8)]   = h1;
    }
    // ---- stage rpe^T into Ks rows 0..7 (row=m, col=d), zero rows 8..15, addr-swizzled ----
    if (t < 64) {
        float4 r0 = *(const float4*)(rpe + t*8);
        float4 r1 = *(const float4*)(rpe + t*8 + 4);
        const int gr = t >> 3, go = t & 7;
        float vals[8] = {r0.x, r0.y, r0.z, r0.w, r1.x, r1.y, r1.z, r1.w};
#pragma unroll
        for (int m = 0; m < 8; m++)
            Ks[m*64 + ((gr ^ (m & 7)) * 8) + go] = f2bf(vals[m]);
    } else if (t < 128) {
        int idx = t - 64;
        int m = 8 + (idx >> 3), g = idx & 7;
        *(u8s*)&Ks[m*64 + ((g ^ (m & 7)) * 8)] = (u8s)0;
    }
    __syncthreads();

    // ---- Q A-fragments (held all K-tiles) ----
    s8bf qf0 = *(s8bf*)&Vs[(row_w + lc)*64 + gA];
    s8bf qf1 = *(s8bf*)&Vs[(row_w + lc)*64 + gB];

    // ---- lut = Q @ rpe via MFMA (wave-private rows; qf/rf consumed HERE -> complete before
    //      first SBAR, so first STAGEA may overwrite Ks/Vs safely) ----
    {
        s8bf rf0 = *(s8bf*)&Ks[lc*64 + gA];
        s8bf rf1 = *(s8bf*)&Ks[lc*64 + gB];
        v4f la = (v4f){0.f, 0.f, 0.f, 0.f};
        la = __builtin_amdgcn_mfma_f32_16x16x32_bf16(qf0, rf0, la, 0, 0, 0);
        la = __builtin_amdgcn_mfma_f32_16x16x32_bf16(qf1, rf1, la, 0, 0, 0);
        if (lc < 8) {
#pragma unroll
            for (int r = 0; r < 4; r++)
                lut[(row_w + lq*4 + r)*LUTS + lc] = la[r];
        }
    }

    int myrow = i0 + row_w + lc; if (myrow > N_ - 1) myrow = N_ - 1;   // lane's Q-row (clamped)
    const unsigned char* bkrow = bucketT + (size_t)myrow * NPAD;
    const int lutbase = (row_w + lc) * LUTS;
    // per-lane j base within tile for quadrant t4: 32*(t4>>1) + 4*(t4&1) + 8*lq
    const int jb0 = 8*lq, jb1 = 8*lq + 4, jb2 = 8*lq + 32, jb3 = 8*lq + 36;
    unsigned bk4[4];
    bk4[0] = *(const unsigned*)(bkrow + jb0);
    bk4[1] = *(const unsigned*)(bkrow + jb1);
    bk4[2] = *(const unsigned*)(bkrow + jb2);
    bk4[3] = *(const unsigned*)(bkrow + jb3);

    // ---- STAGEA via global_load_lds (R10-verified): linear dest, sigma+XOR pre-permuted source.
    // Lane l covers slot s = base + l/8, granule g = l&7. K content at (s,g) =
    // K[sigma^-1(s)] granule g^(s&7); sigma^-1: s bits {c=0:1, a=2:3, b=4, d=5} -> j=32d+8a+4b+c.
    auto STAGEA = [&](int jbase) {
#pragma unroll
        for (int i = 0; i < 2; i++) {
            int s = w*16 + i*8 + (lane >> 3);
            int jr = 32*(s>>5) + 8*((s>>2)&3) + 4*((s>>4)&1) + (s&3);
            int gj = jbase + jr; if (gj > N_ - 1) gj = N_ - 1;
            GLOAD16(kp + (size_t)gj * HD_ + (((lane&7) ^ (s&7)) * 8), &Ks[(w*16 + i*8)*64]);
        }
#pragma unroll
        for (int i = 0; i < 2; i++) {
            int d = w*16 + i*8 + (lane >> 3);
            GLOAD16(vp + (size_t)d * NPADV + jbase + (((lane&7) ^ (d&7)) * 8), &Vs[(w*16 + i*8)*64]);
        }
    };

    v4f o[4];
    float lsum = 0.f;
#pragma unroll
    for (int dt = 0; dt < 4; dt++) o[dt] = (v4f){0.f, 0.f, 0.f, 0.f};

    // ---- one tile: QK^T -> softmax (bk4) -> issue next bucket loads -> PV ----
    auto TILE = [&](int nextj, bool tail) {
        v4f acc[4];
#pragma unroll
        for (int t4 = 0; t4 < 4; t4++) acc[t4] = (v4f){0.f, 0.f, 0.f, 0.f};
#pragma unroll
        for (int t4 = 0; t4 < 4; t4++) {
            s8bf kf0 = *(const s8bf*)&Ks[(t4*16 + lc)*64 + gA];
            s8bf kf1 = *(const s8bf*)&Ks[(t4*16 + lc)*64 + gB];
            acc[t4] = __builtin_amdgcn_mfma_f32_16x16x32_bf16(kf0, qf0, acc[t4], 0, 0, 0);
            acc[t4] = __builtin_amdgcn_mfma_f32_16x16x32_bf16(kf1, qf1, acc[t4], 0, 0, 0);
        }
        unsigned pw[8];
        if (!tail) {
#pragma unroll
            for (int t4 = 0; t4 < 4; t4++) {
                int k0b = (bk4[t4]      ) & 0xFF; float p0 = __expf(acc[t4][0] + lut[lutbase + k0b]);
                int k1b = (bk4[t4] >>  8) & 0xFF; float p1 = __expf(acc[t4][1] + lut[lutbase + k1b]);
                int k2b = (bk4[t4] >> 16) & 0xFF; float p2 = __expf(acc[t4][2] + lut[lutbase + k2b]);
                int k3b = (bk4[t4] >> 24)       ; float p3 = __expf(acc[t4][3] + lut[lutbase + k3b]);
                lsum += (p0 + p1) + (p2 + p3);
                pw[t4*2]     = packbf_hu(p0, p1);
                pw[t4*2 + 1] = packbf_hu(p2, p3);
            }
        } else {
            const int jbs[4] = {jb0, jb1, jb2, jb3};
#pragma unroll
            for (int t4 = 0; t4 < 4; t4++) {
                float pv[4];
#pragma unroll
                for (int r = 0; r < 4; r++) {
                    int bk = (bk4[t4] >> (8*r)) & 0xFF;
                    float p = __expf(acc[t4][r] + lut[lutbase + bk]);
                    if ((jbs[t4] + r) > 0) p = 0.f;   // only j==1024 valid
                    lsum += p;
                    pv[r] = p;
                }
                pw[t4*2]     = packbf_hu(pv[0], pv[1]);
                pw[t4*2 + 1] = packbf_hu(pv[2], pv[3]);
            }
        }
        if (nextj >= 0) {   // issue next tile's bucket loads AFTER softmax consumed bk4
            bk4[0] = *(const unsigned*)(bkrow + nextj + jb0);
            bk4[1] = *(const unsigned*)(bkrow + nextj + jb1);
            bk4[2] = *(const unsigned*)(bkrow + nextj + jb2);
            bk4[3] = *(const unsigned*)(bkrow + nextj + jb3);
        }
        s8bf pf0 = *(s8bf*)&pw[0];
        s8bf pf1 = *(s8bf*)&pw[4];
#pragma unroll
        for (int dt = 0; dt < 4; dt++) {
            s8bf vf0 = *(const s8bf*)&Vs[(dt*16 + lc)*64 + gA];
            s8bf vf1 = *(const s8bf*)&Vs[(dt*16 + lc)*64 + gB];
            o[dt] = __builtin_amdgcn_mfma_f32_16x16x32_bf16(pf0, vf0, o[dt], 0, 0, 0);
            o[dt] = __builtin_amdgcn_mfma_f32_16x16x32_bf16(pf1, vf1, o[dt], 0, 0, 0);
        }
    };

    // ---- main loop: single-buffer {SBAR; stage; vmcnt(0); SBAR; compute} ----
    for (int jt = 0; jt < 16; jt++) {
        SBAR();             // all waves' frag reads of prev tile complete (consumed by MFMAs)
        STAGEA(jt * 64);
        VMW(0);             // staging landed (drain hidden by 32-wave TLP)
        SBAR();             // visible to all waves
        TILE(jt * 64 + 64, false);
    }
    // peeled tile 16 (j0=1024; only j==1024 valid; bk4 = bucket(1024) from jt=15)
    SBAR();
    STAGEA(1024);
    VMW(0);
    SBAR();
    TILE(-1, true);

    // ---- epilogue: lsum partial over this lane's j-subset; reduce over lq, bcast via lut col 8 ----
    lsum += __shfl_xor(lsum, 16);
    lsum += __shfl_xor(lsum, 32);          // lanes {lc,lc+16,lc+32,lc+48} hold total sum(row)
    if (lq == 0) lut[(row_w + lc)*LUTS + 8] = lsum;
    __builtin_amdgcn_s_waitcnt(0);          // lgkm drain before same-wave read (wave-private rows)
#pragma unroll
    for (int r = 0; r < 4; r++) {
        int i = i0 + row_w + lq*4 + r;
        if (i < N_) {
            float inv = 1.0f / lut[(row_w + lq*4 + r)*LUTS + 8];
#pragma unroll
            for (int dt = 0; dt < 4; dt++)
                ao[((size_t)(b*N_ + i))*C_ + hh*HD_ + dt*16 + lc] = f2bf(o[dt][r] * inv);
        }
    }
}

// ---------------- proj: out(8200x768) = aob @ wprojb^T + bias, f32 out ----------------
// same T3+T4 pipeline + T1 bijective XCD swizzle (nwg=390: q=48, r=6)
__global__ __launch_bounds__(256) void proj_kernel(
        const ushort_t* __restrict__ ab, const ushort_t* __restrict__ wb,
        const float* __restrict__ bias, float* __restrict__ out) {
    __shared__ __align__(16) ushort_t As0[128*64];
    __shared__ __align__(16) ushort_t Bs0[128*64];
    __shared__ __align__(16) ushort_t As1[128*64];
    __shared__ __align__(16) ushort_t Bs1[128*64];
    const int L = blockIdx.x + blockIdx.y * 65;
    const int xcd = L & 7, idx = L >> 3;
    const int wg = (xcd < 6 ? xcd * 49 : 6 * 49 + (xcd - 6) * 48) + idx;
    const int m0 = (wg / 6) * 128, c0 = (wg % 6) * 128;
    const int t = threadIdx.x;
    const int w = t >> 6, lane = t & 63, lc = lane & 15, lq = lane >> 4;
    const int wm = (w >> 1) * 64, wn = (w & 1) * 64;
    const int srow8 = w * 32 + (lane >> 3);
    const int gsw8  = (((lane & 7) ^ (lane >> 3)) & 7) * 8;

    v4f acc[4][4];
#pragma unroll
    for (int mt = 0; mt < 4; mt++)
#pragma unroll
        for (int nt = 0; nt < 4; nt++) acc[mt][nt] = (v4f){0.f, 0.f, 0.f, 0.f};

    auto STAGE = [&](ushort_t* Ad, ushort_t* Bd, int k0) {
#pragma unroll
        for (int i = 0; i < 4; i++) {
            int row = srow8 + i * 8;
            int m = m0 + row; if (m > NTOK - 1) m = NTOK - 1;
            GLOAD16(ab + (size_t)m * C_ + k0 + gsw8,           &Ad[(w*32 + i*8) * 64]);
            GLOAD16(wb + (size_t)(c0 + row) * C_ + k0 + gsw8,  &Bd[(w*32 + i*8) * 64]);
        }
    };
    auto COMPUTE = [&](const ushort_t* A, const ushort_t* B) {
#pragma unroll
        for (int kk = 0; kk < 64; kk += 32) {
            s8bf af[4], bf[4];
#pragma unroll
            for (int mt = 0; mt < 4; mt++)
                af[mt] = *(const s8bf*)&A[(wm + mt*16 + lc) * 64 + ((((kk>>3) + lq) ^ (lc & 7)) * 8)];
#pragma unroll
            for (int nt = 0; nt < 4; nt++)
                bf[nt] = *(const s8bf*)&B[(wn + nt*16 + lc) * 64 + ((((kk>>3) + lq) ^ (lc & 7)) * 8)];
#pragma unroll
            for (int mt = 0; mt < 4; mt++)
#pragma unroll
                for (int nt = 0; nt < 4; nt++)
                    acc[mt][nt] = __builtin_amdgcn_mfma_f32_16x16x32_bf16(af[mt], bf[nt], acc[mt][nt], 0, 0, 0);
        }
    };

    STAGE(As0, Bs0, 0);
#pragma unroll
    for (int it = 0; it < 6; ++it) {
        const int k0 = it * 128;
        if (k0 + 64 < C_) {
            STAGE(As1, Bs1, k0 + 64);
            asm volatile("s_waitcnt vmcnt(8)" ::: "memory");
        } else {
            asm volatile("s_waitcnt vmcnt(0)" ::: "memory");
        }
        SBAR();
        COMPUTE(As0, Bs0);
        SBAR();
        if (k0 + 128 < C_) {
            STAGE(As0, Bs0, k0 + 128);
            asm volatile("s_waitcnt vmcnt(8)" ::: "memory");
        } else {
            asm volatile("s_waitcnt vmcnt(0)" ::: "memory");
        }
        SBAR();
        COMPUTE(As1, Bs1);
        if (it < 5) SBAR();
    }

    float pb[4];
#pragma unroll
    for (int nt = 0; nt < 4; nt++) pb[nt] = bias[c0 + wn + nt*16 + lc];
#pragma unroll
    for (int mt = 0; mt < 4; mt++) {
#pragma unroll
        for (int r = 0; r < 4; r++) {
            int m = m0 + wm + mt*16 + lq*4 + r;
            if (m >= NTOK) continue;
#pragma unroll
            for (int nt = 0; nt < 4; nt++) {
                int c = c0 + wn + nt*16 + lc;
                out[(size_t)m * C_ + c] = acc[mt][nt][r] + pb[nt];
            }
        }
    }
}

extern "C" void kernel_launch(void* const* d_in, const int* in_sizes, int n_in,
                              void* d_out, int out_size, void* d_ws, size_t ws_size,
                              hipStream_t stream) {
    const float* x      = (const float*)d_in[0];
    const float* qkv_w  = (const float*)d_in[1];
    const float* proj_w = (const float*)d_in[2];
    const float* proj_b = (const float*)d_in[3];
    const float* rpe_w  = (const float*)d_in[4];
    float* out = (float*)d_out;

    char* ws = (char*)d_ws;
    ushort_t* xb   = (ushort_t*)(ws + XB_OFF_B);
    ushort_t* wqkv = (ushort_t*)(ws + WQKV_OFF_B);
    ushort_t* wprj = (ushort_t*)(ws + WPROJ_OFF_B);
    ushort_t* qb   = (ushort_t*)(ws + QB_OFF_B);
    ushort_t* kb   = (ushort_t*)(ws + KB_OFF_B);
    ushort_t* aob  = (ushort_t*)(ws + AOB_OFF_B);
    ushort_t* vt   = (ushort_t*)(ws + VT_OFF_B);
    unsigned char* bucketT = (unsigned char*)(ws + BUCKET_OFF_B);

    const int ncast = (NTOK*C_ + 3*C_*C_ + C_*C_) / 8;
    bucket_kernel<<<dim3((N_*NPAD + 255)/256), 256, 0, stream>>>(bucketT);
    cast_kernel<<<dim3((ncast + 255)/256), 256, 0, stream>>>(x, qkv_w, proj_w, xb, wqkv, wprj);
    qkv_kernel<<<dim3(65, 18), 256, 0, stream>>>(xb, wqkv, qb, kb, vt);
    attn_kernel<<<dim3(96, 17), 256, 0, stream>>>(qb, kb, vt, rpe_w, bucketT, aob);
    proj_kernel<<<dim3(65, 6), 256, 0, stream>>>(aob, wprj, proj_b, out);
}

// Round 13
// 224.893 us; speedup vs baseline: 1.0487x; 1.0126x over previous
//
#include <hip/hip_runtime.h>
#include <math.h>

#define B_    8
#define N_    1025
#define H_    12
#define HD_   64
#define C_    768
#define BH_   (B_*H_)
#define NTOK  (B_*N_)          // 8200
#define SCALE 0.125f
#define NPAD  1092             // bucketT row stride (mult of 4); table is SYMMETRIC: [a][b]=bucket(a,b)
#define NPADV 1088             // vt row stride (17*64)

#define QKV_ELEMS (BH_*N_*HD_)         // 6,297,600

// ws layout (bytes)
#define XB_OFF_B     ((size_t)0)
#define WQKV_OFF_B   (XB_OFF_B + (size_t)NTOK*C_*2)
#define WPROJ_OFF_B  (WQKV_OFF_B + (size_t)3*C_*C_*2)
#define QB_OFF_B     (WPROJ_OFF_B + (size_t)C_*C_*2)
#define KB_OFF_B     (QB_OFF_B + (size_t)QKV_ELEMS*2)
#define AOB_OFF_B    (KB_OFF_B + (size_t)QKV_ELEMS*2)
#define VT_OFF_B     (AOB_OFF_B + (size_t)QKV_ELEMS*2)
#define BUCKET_OFF_B (VT_OFF_B + (size_t)BH_*HD_*NPADV*2)

typedef __attribute__((ext_vector_type(8))) short s8bf;
typedef __attribute__((ext_vector_type(8))) unsigned short u8s;
typedef __attribute__((ext_vector_type(4))) float v4f;
typedef unsigned short ushort_t;

// async global -> LDS, 16B per lane. LDS dest must be wave-uniform base
// (HW writes base + lane*16); global src is per-lane.
#define GLOAD16(gp, lp) __builtin_amdgcn_global_load_lds( \
    (const __attribute__((address_space(1))) unsigned int*)(gp), \
    (__attribute__((address_space(3))) unsigned int*)(lp), 16, 0, 0)

// raw workgroup barrier with compiler memory fence (no vmcnt drain, unlike __syncthreads)
#define SBAR() do { \
    __builtin_amdgcn_sched_barrier(0); \
    asm volatile("s_barrier" ::: "memory"); \
    __builtin_amdgcn_sched_barrier(0); \
} while (0)
// pinned counted vmcnt (sched_barrier blocks motion across — rule 18/m152)
#define VMW(N) do { \
    __builtin_amdgcn_sched_barrier(0); \
    asm volatile("s_waitcnt vmcnt(" #N ")" ::: "memory"); \
    __builtin_amdgcn_sched_barrier(0); \
} while (0)

// hand-RNE f32->bf16 (KEEP for all persistent tensors: v_cvt_pk_bf16_f32 asm path
// failed absmax in R3 — rounding-mode bias accumulated coherently)
__device__ __forceinline__ unsigned short f2bf(float x) {
    union { float f; unsigned u; } v; v.f = x;
    unsigned r = v.u + 0x7FFFu + ((v.u >> 16) & 1u);
    return (unsigned short)(r >> 16);
}
// round-half-up pack of two NONNEGATIVE floats (P values): differs from RNE only on
// exact ties (measure-zero after exp; no coherent bias). 5 ops/pair vs ~11.
__device__ __forceinline__ unsigned packbf_hu(float lo, float hi) {
    union { float f; unsigned u; } a, b; a.f = lo; b.f = hi;
    return ((a.u + 0x8000u) >> 16) | ((b.u + 0x8000u) & 0xFFFF0000u);
}

// ---- bucketT[a][b] = bucket(a,b), integer-exact & SYMMETRIC: {d2=0:0, d2<=2:1, d2<=12:2, else 3}, cls:7 ----
__global__ void bucket_kernel(unsigned char* __restrict__ bucketT) {
    int tid = blockIdx.x * 256 + threadIdx.x;
    if (tid >= N_ * NPAD) return;
    unsigned ut = (unsigned)tid;
    int j = ut / (unsigned)NPAD, i = ut % (unsigned)NPAD;
    if (i >= N_) i = N_ - 1;
    int bk;
    if (i < 1 || j < 1) {
        bk = 7;
    } else {
        int pi = i - 1, pj = j - 1;
        int dy = (pi >> 5) - (pj >> 5);
        int dx = (pi & 31) - (pj & 31);
        int d2 = dy*dy + dx*dx;
        bk = (d2 == 0) ? 0 : ((d2 <= 2) ? 1 : ((d2 <= 12) ? 2 : 3));
    }
    bucketT[tid] = (unsigned char)bk;
}

// ---------------- fused f32 -> bf16 cast (x, qkv_w, proj_w) ----------------
__global__ __launch_bounds__(256) void cast_kernel(
        const float* __restrict__ x, const float* __restrict__ w1,
        const float* __restrict__ w2,
        ushort_t* __restrict__ xb, ushort_t* __restrict__ w1b,
        ushort_t* __restrict__ w2b) {
    const int NX = NTOK * C_ / 8, NW1 = 3 * C_ * C_ / 8, NW2 = C_ * C_ / 8;
    int g = blockIdx.x * 256 + threadIdx.x;
    const float* src; ushort_t* dst; int idx;
    if (g < NX)                 { src = x;  dst = xb;  idx = g; }
    else if (g < NX + NW1)      { src = w1; dst = w1b; idx = g - NX; }
    else if (g < NX + NW1 + NW2){ src = w2; dst = w2b; idx = g - NX - NW1; }
    else return;
    size_t off = (size_t)idx * 8;
    float4 a = *(const float4*)(src + off);
    float4 c = *(const float4*)(src + off + 4);
    __align__(16) ushort_t h[8] = {f2bf(a.x), f2bf(a.y), f2bf(a.z), f2bf(a.w),
                                   f2bf(c.x), f2bf(c.y), f2bf(c.z), f2bf(c.w)};
    *(u8s*)(dst + off) = *(u8s*)h;
}

// ---------------- bf16 MFMA GEMM: 128x128 tile, BK=64, SINGLE-BUFFER global_load_lds ----------------
// T1 XCD swizzle (bijective, m204) made loads L2-resident (FETCH 126->49MB), so the
// per-phase vmcnt(0) drain is ~200cy and cross-block hidden. Single buffer = 32KB LDS
// -> 4 blocks/CU (was 2 with dbuf): packs the bursty LDS-read phases across blocks
// (R12: phase LDS burst 1540cy vs MFMA 310cy -> MfmaUtil capped ~20% at 2 blocks).
// Same pattern validated on attn in R12 (70.9 -> <68) and by m97 (874 TF, full-drain).
__global__ __launch_bounds__(256) void qkv_kernel(
        const ushort_t* __restrict__ xb, const ushort_t* __restrict__ wb,
        ushort_t* __restrict__ qb, ushort_t* __restrict__ kb, ushort_t* __restrict__ vt) {
    __shared__ __align__(16) ushort_t As[128*64];
    __shared__ __align__(16) ushort_t Bs[128*64];
    // bijective XCD remap: nwg=1170, q=146, r=2
    const int L = blockIdx.x + blockIdx.y * 65;
    const int xcd = L & 7, idx = L >> 3;
    const int wg = (xcd < 2 ? xcd * 147 : 2 * 147 + (xcd - 2) * 146) + idx;
    const int m0 = (wg / 18) * 128, c0 = (wg % 18) * 128;
    const int t = threadIdx.x;
    const int w = t >> 6, lane = t & 63, lc = lane & 15, lq = lane >> 4;
    const int wm = (w >> 1) * 64, wn = (w & 1) * 64;
    const int srow8 = w * 32 + (lane >> 3);                    // + i*8 = row within tile
    const int gsw8  = (((lane & 7) ^ (lane >> 3)) & 7) * 8;    // swizzled source col (ushorts)

    v4f acc[4][4];
#pragma unroll
    for (int mt = 0; mt < 4; mt++)
#pragma unroll
        for (int nt = 0; nt < 4; nt++) acc[mt][nt] = (v4f){0.f, 0.f, 0.f, 0.f};

    auto STAGE = [&](int k0) {
#pragma unroll
        for (int i = 0; i < 4; i++) {
            int row = srow8 + i * 8;
            int m = m0 + row; if (m > NTOK - 1) m = NTOK - 1;   // clamp: dup reads, rows masked in epilogue
            GLOAD16(xb + (size_t)m * C_ + k0 + gsw8,           &As[(w*32 + i*8) * 64]);
            GLOAD16(wb + (size_t)(c0 + row) * C_ + k0 + gsw8,  &Bs[(w*32 + i*8) * 64]);
        }
    };
    auto COMPUTE = [&]() {
#pragma unroll
        for (int kk = 0; kk < 64; kk += 32) {
            s8bf af[4], bf[4];
#pragma unroll
            for (int mt = 0; mt < 4; mt++)
                af[mt] = *(const s8bf*)&As[(wm + mt*16 + lc) * 64 + ((((kk>>3) + lq) ^ (lc & 7)) * 8)];
#pragma unroll
            for (int nt = 0; nt < 4; nt++)
                bf[nt] = *(const s8bf*)&Bs[(wn + nt*16 + lc) * 64 + ((((kk>>3) + lq) ^ (lc & 7)) * 8)];
#pragma unroll
            for (int mt = 0; mt < 4; mt++)
#pragma unroll
                for (int nt = 0; nt < 4; nt++)
                    acc[mt][nt] = __builtin_amdgcn_mfma_f32_16x16x32_bf16(af[mt], bf[nt], acc[mt][nt], 0, 0, 0);
        }
    };

    for (int it = 0; it < 12; ++it) {
        if (it) SBAR();     // prev tile's ds_reads complete (consumed before wave reached here)
        STAGE(it * 64);
        VMW(0);             // own loads landed (L2-hit drain, cross-block hidden)
        SBAR();             // all waves' staging visible
        COMPUTE();
    }

#pragma unroll
    for (int mt = 0; mt < 4; mt++) {
#pragma unroll
        for (int r = 0; r < 4; r++) {
            int m = m0 + wm + mt*16 + lq*4 + r;
            if (m >= NTOK) continue;
            unsigned um = (unsigned)m;
            int b = um / (unsigned)N_, n = um % (unsigned)N_;
#pragma unroll
            for (int nt = 0; nt < 4; nt++) {
                int c = c0 + wn + nt*16 + lc;
                int comp = c / C_, rem = c % C_;
                int h = rem >> 6, d0 = rem & 63;
                float val = acc[mt][nt][r] * ((comp == 0) ? SCALE : 1.0f);
                if (comp == 2) {
                    vt[((size_t)((b*H_ + h)*HD_ + d0))*NPADV + n] = f2bf(val);
                } else {
                    ushort_t* dst = (comp == 0) ? qb : kb;
                    dst[((size_t)((b*H_ + h)*N_ + n))*HD_ + d0] = f2bf(val);
                }
            }
        }
    }
}

// ---------------- attention: R9 shape + gload_lds single-buffer (R12, kept) ----------------
#define LUTS 9

__global__ __launch_bounds__(256) void attn_kernel(
        const ushort_t* __restrict__ qb, const ushort_t* __restrict__ kb,
        const ushort_t* __restrict__ vt, const float* __restrict__ rpe,
        const unsigned char* __restrict__ bucketT, ushort_t* __restrict__ ao) {
    __shared__ __align__(16) ushort_t Ks[64*64];    // prologue alias rows 0..15: rpe^T
    __shared__ __align__(16) ushort_t Vs[64*64];    // prologue alias: Q tile
    __shared__ float lut[64*LUTS];                  // col 8: lsum broadcast (epilogue)

    const int bh = blockIdx.x, it0 = blockIdx.y;    // bh-major: all i-tiles of bh on one XCD
    const int b  = bh / H_, hh = bh % H_;
    const int i0 = it0 * 64;
    const int t  = threadIdx.x;
    const int w  = t >> 6, lane = t & 63, lc = lane & 15, lq = lane >> 4;
    const int row_w = w * 16;                       // wave strip (16 rows)
    const int rs = lc & 7;                          // read-swizzle key (all frag rows ≡ lc mod 8)
    const int gA = ((lq ^ rs) & 7) * 8;             // frag0 swizzled col (granule lq)
    const int gB = (((lq + 4) ^ rs) & 7) * 8;       // frag1 swizzled col (granule 4+lq)

    const ushort_t* qp = qb + (size_t)bh * N_ * HD_;
    const ushort_t* kp = kb + (size_t)bh * N_ * HD_;
    const ushort_t* vp = vt + (size_t)bh * HD_ * NPADV;

    // ---- stage Q into Vs (zero rows >= N), addr-swizzled ----
    {
        int row = t >> 2, g0 = (t & 3) * 2, qrs = row & 7;
        int gi = i0 + row;
        u8s h0 = (u8s)0, h1 = (u8s)0;
        if (gi < N_) {
            h0 = *(const u8s*)(qp + (size_t)gi * HD_ + g0*8);
            h1 = *(const u8s*)(qp + (size_t)gi * HD_ + g0*8 + 8);
        }
        *(u8s*)&Vs[row*64 + ((g0 ^ qrs) * 8)]       = h0;
        *(u8s*)&Vs[row*64 + (((g0+1) ^ qrs) * 8)]   = h1;
    }
    // ---- stage rpe^T into Ks rows 0..7 (row=m, col=d), zero rows 8..15, addr-swizzled ----
    if (t < 64) {
        float4 r0 = *(const float4*)(rpe + t*8);
        float4 r1 = *(const float4*)(rpe + t*8 + 4);
        const int gr = t >> 3, go = t & 7;
        float vals[8] = {r0.x, r0.y, r0.z, r0.w, r1.x, r1.y, r1.z, r1.w};
#pragma unroll
        for (int m = 0; m < 8; m++)
            Ks[m*64 + ((gr ^ (m & 7)) * 8) + go] = f2bf(vals[m]);
    } else if (t < 128) {
        int idx = t - 64;
        int m = 8 + (idx >> 3), g = idx & 7;
        *(u8s*)&Ks[m*64 + ((g ^ (m & 7)) * 8)] = (u8s)0;
    }
    __syncthreads();

    // ---- Q A-fragments (held all K-tiles) ----
    s8bf qf0 = *(s8bf*)&Vs[(row_w + lc)*64 + gA];
    s8bf qf1 = *(s8bf*)&Vs[(row_w + lc)*64 + gB];

    // ---- lut = Q @ rpe via MFMA (wave-private rows; qf/rf consumed here, before first SBAR) ----
    {
        s8bf rf0 = *(s8bf*)&Ks[lc*64 + gA];
        s8bf rf1 = *(s8bf*)&Ks[lc*64 + gB];
        v4f la = (v4f){0.f, 0.f, 0.f, 0.f};
        la = __builtin_amdgcn_mfma_f32_16x16x32_bf16(qf0, rf0, la, 0, 0, 0);
        la = __builtin_amdgcn_mfma_f32_16x16x32_bf16(qf1, rf1, la, 0, 0, 0);
        if (lc < 8) {
#pragma unroll
            for (int r = 0; r < 4; r++)
                lut[(row_w + lq*4 + r)*LUTS + lc] = la[r];
        }
    }

    int myrow = i0 + row_w + lc; if (myrow > N_ - 1) myrow = N_ - 1;   // lane's Q-row (clamped)
    const unsigned char* bkrow = bucketT + (size_t)myrow * NPAD;
    const int lutbase = (row_w + lc) * LUTS;
    // per-lane j base within tile for quadrant t4: 32*(t4>>1) + 4*(t4&1) + 8*lq
    const int jb0 = 8*lq, jb1 = 8*lq + 4, jb2 = 8*lq + 32, jb3 = 8*lq + 36;
    unsigned bk4[4];
    bk4[0] = *(const unsigned*)(bkrow + jb0);
    bk4[1] = *(const unsigned*)(bkrow + jb1);
    bk4[2] = *(const unsigned*)(bkrow + jb2);
    bk4[3] = *(const unsigned*)(bkrow + jb3);

    // ---- STAGEA via global_load_lds: linear dest, sigma+XOR pre-permuted source.
    // sigma^-1: s bits {c=0:1, a=2:3, b=4, d=5} -> j=32d+8a+4b+c.
    auto STAGEA = [&](int jbase) {
#pragma unroll
        for (int i = 0; i < 2; i++) {
            int s = w*16 + i*8 + (lane >> 3);
            int jr = 32*(s>>5) + 8*((s>>2)&3) + 4*((s>>4)&1) + (s&3);
            int gj = jbase + jr; if (gj > N_ - 1) gj = N_ - 1;
            GLOAD16(kp + (size_t)gj * HD_ + (((lane&7) ^ (s&7)) * 8), &Ks[(w*16 + i*8)*64]);
        }
#pragma unroll
        for (int i = 0; i < 2; i++) {
            int d = w*16 + i*8 + (lane >> 3);
            GLOAD16(vp + (size_t)d * NPADV + jbase + (((lane&7) ^ (d&7)) * 8), &Vs[(w*16 + i*8)*64]);
        }
    };

    v4f o[4];
    float lsum = 0.f;
#pragma unroll
    for (int dt = 0; dt < 4; dt++) o[dt] = (v4f){0.f, 0.f, 0.f, 0.f};

    // ---- one tile: QK^T -> softmax (bk4) -> issue next bucket loads -> PV ----
    auto TILE = [&](int nextj, bool tail) {
        v4f acc[4];
#pragma unroll
        for (int t4 = 0; t4 < 4; t4++) acc[t4] = (v4f){0.f, 0.f, 0.f, 0.f};
#pragma unroll
        for (int t4 = 0; t4 < 4; t4++) {
            s8bf kf0 = *(const s8bf*)&Ks[(t4*16 + lc)*64 + gA];
            s8bf kf1 = *(const s8bf*)&Ks[(t4*16 + lc)*64 + gB];
            acc[t4] = __builtin_amdgcn_mfma_f32_16x16x32_bf16(kf0, qf0, acc[t4], 0, 0, 0);
            acc[t4] = __builtin_amdgcn_mfma_f32_16x16x32_bf16(kf1, qf1, acc[t4], 0, 0, 0);
        }
        unsigned pw[8];
        if (!tail) {
#pragma unroll
            for (int t4 = 0; t4 < 4; t4++) {
                int k0b = (bk4[t4]      ) & 0xFF; float p0 = __expf(acc[t4][0] + lut[lutbase + k0b]);
                int k1b = (bk4[t4] >>  8) & 0xFF; float p1 = __expf(acc[t4][1] + lut[lutbase + k1b]);
                int k2b = (bk4[t4] >> 16) & 0xFF; float p2 = __expf(acc[t4][2] + lut[lutbase + k2b]);
                int k3b = (bk4[t4] >> 24)       ; float p3 = __expf(acc[t4][3] + lut[lutbase + k3b]);
                lsum += (p0 + p1) + (p2 + p3);
                pw[t4*2]     = packbf_hu(p0, p1);
                pw[t4*2 + 1] = packbf_hu(p2, p3);
            }
        } else {
            const int jbs[4] = {jb0, jb1, jb2, jb3};
#pragma unroll
            for (int t4 = 0; t4 < 4; t4++) {
                float pv[4];
#pragma unroll
                for (int r = 0; r < 4; r++) {
                    int bk = (bk4[t4] >> (8*r)) & 0xFF;
                    float p = __expf(acc[t4][r] + lut[lutbase + bk]);
                    if ((jbs[t4] + r) > 0) p = 0.f;   // only j==1024 valid
                    lsum += p;
                    pv[r] = p;
                }
                pw[t4*2]     = packbf_hu(pv[0], pv[1]);
                pw[t4*2 + 1] = packbf_hu(pv[2], pv[3]);
            }
        }
        if (nextj >= 0) {   // issue next tile's bucket loads AFTER softmax consumed bk4
            bk4[0] = *(const unsigned*)(bkrow + nextj + jb0);
            bk4[1] = *(const unsigned*)(bkrow + nextj + jb1);
            bk4[2] = *(const unsigned*)(bkrow + nextj + jb2);
            bk4[3] = *(const unsigned*)(bkrow + nextj + jb3);
        }
        s8bf pf0 = *(s8bf*)&pw[0];
        s8bf pf1 = *(s8bf*)&pw[4];
#pragma unroll
        for (int dt = 0; dt < 4; dt++) {
            s8bf vf0 = *(const s8bf*)&Vs[(dt*16 + lc)*64 + gA];
            s8bf vf1 = *(const s8bf*)&Vs[(dt*16 + lc)*64 + gB];
            o[dt] = __builtin_amdgcn_mfma_f32_16x16x32_bf16(pf0, vf0, o[dt], 0, 0, 0);
            o[dt] = __builtin_amdgcn_mfma_f32_16x16x32_bf16(pf1, vf1, o[dt], 0, 0, 0);
        }
    };

    // ---- main loop: single-buffer {SBAR; stage; vmcnt(0); SBAR; compute} ----
    for (int jt = 0; jt < 16; jt++) {
        SBAR();             // all waves' frag reads of prev tile complete
        STAGEA(jt * 64);
        VMW(0);             // staging landed (drain hidden by 32-wave TLP)
        SBAR();             // visible to all waves
        TILE(jt * 64 + 64, false);
    }
    // peeled tile 16 (j0=1024; only j==1024 valid; bk4 = bucket(1024) from jt=15)
    SBAR();
    STAGEA(1024);
    VMW(0);
    SBAR();
    TILE(-1, true);

    // ---- epilogue: lsum partial over this lane's j-subset; reduce over lq, bcast via lut col 8 ----
    lsum += __shfl_xor(lsum, 16);
    lsum += __shfl_xor(lsum, 32);          // lanes {lc,lc+16,lc+32,lc+48} hold total sum(row)
    if (lq == 0) lut[(row_w + lc)*LUTS + 8] = lsum;
    __builtin_amdgcn_s_waitcnt(0);          // lgkm drain before same-wave read (wave-private rows)
#pragma unroll
    for (int r = 0; r < 4; r++) {
        int i = i0 + row_w + lq*4 + r;
        if (i < N_) {
            float inv = 1.0f / lut[(row_w + lq*4 + r)*LUTS + 8];
#pragma unroll
            for (int dt = 0; dt < 4; dt++)
                ao[((size_t)(b*N_ + i))*C_ + hh*HD_ + dt*16 + lc] = f2bf(o[dt][r] * inv);
        }
    }
}

// ---------------- proj: out(8200x768) = aob @ wprojb^T + bias, f32 out ----------------
// single-buffer (32KB -> 4 blocks/CU) + T1 bijective XCD swizzle (nwg=390: q=48, r=6)
__global__ __launch_bounds__(256) void proj_kernel(
        const ushort_t* __restrict__ ab, const ushort_t* __restrict__ wb,
        const float* __restrict__ bias, float* __restrict__ out) {
    __shared__ __align__(16) ushort_t As[128*64];
    __shared__ __align__(16) ushort_t Bs[128*64];
    const int L = blockIdx.x + blockIdx.y * 65;
    const int xcd = L & 7, idx = L >> 3;
    const int wg = (xcd < 6 ? xcd * 49 : 6 * 49 + (xcd - 6) * 48) + idx;
    const int m0 = (wg / 6) * 128, c0 = (wg % 6) * 128;
    const int t = threadIdx.x;
    const int w = t >> 6, lane = t & 63, lc = lane & 15, lq = lane >> 4;
    const int wm = (w >> 1) * 64, wn = (w & 1) * 64;
    const int srow8 = w * 32 + (lane >> 3);
    const int gsw8  = (((lane & 7) ^ (lane >> 3)) & 7) * 8;

    v4f acc[4][4];
#pragma unroll
    for (int mt = 0; mt < 4; mt++)
#pragma unroll
        for (int nt = 0; nt < 4; nt++) acc[mt][nt] = (v4f){0.f, 0.f, 0.f, 0.f};

    auto STAGE = [&](int k0) {
#pragma unroll
        for (int i = 0; i < 4; i++) {
            int row = srow8 + i * 8;
            int m = m0 + row; if (m > NTOK - 1) m = NTOK - 1;
            GLOAD16(ab + (size_t)m * C_ + k0 + gsw8,           &As[(w*32 + i*8) * 64]);
            GLOAD16(wb + (size_t)(c0 + row) * C_ + k0 + gsw8,  &Bs[(w*32 + i*8) * 64]);
        }
    };
    auto COMPUTE = [&]() {
#pragma unroll
        for (int kk = 0; kk < 64; kk += 32) {
            s8bf af[4], bf[4];
#pragma unroll
            for (int mt = 0; mt < 4; mt++)
                af[mt] = *(const s8bf*)&As[(wm + mt*16 + lc) * 64 + ((((kk>>3) + lq) ^ (lc & 7)) * 8)];
#pragma unroll
            for (int nt = 0; nt < 4; nt++)
                bf[nt] = *(const s8bf*)&Bs[(wn + nt*16 + lc) * 64 + ((((kk>>3) + lq) ^ (lc & 7)) * 8)];
#pragma unroll
            for (int mt = 0; mt < 4; mt++)
#pragma unroll
                for (int nt = 0; nt < 4; nt++)
                    acc[mt][nt] = __builtin_amdgcn_mfma_f32_16x16x32_bf16(af[mt], bf[nt], acc[mt][nt], 0, 0, 0);
        }
    };

    for (int it = 0; it < 12; ++it) {
        if (it) SBAR();
        STAGE(it * 64);
        VMW(0);
        SBAR();
        COMPUTE();
    }

    float pb[4];
#pragma unroll
    for (int nt = 0; nt < 4; nt++) pb[nt] = bias[c0 + wn + nt*16 + lc];
#pragma unroll
    for (int mt = 0; mt < 4; mt++) {
#pragma unroll
        for (int r = 0; r < 4; r++) {
            int m = m0 + wm + mt*16 + lq*4 + r;
            if (m >= NTOK) continue;
#pragma unroll
            for (int nt = 0; nt < 4; nt++) {
                int c = c0 + wn + nt*16 + lc;
                out[(size_t)m * C_ + c] = acc[mt][nt][r] + pb[nt];
            }
        }
    }
}

extern "C" void kernel_launch(void* const* d_in, const int* in_sizes, int n_in,
                              void* d_out, int out_size, void* d_ws, size_t ws_size,
                              hipStream_t stream) {
    const float* x      = (const float*)d_in[0];
    const float* qkv_w  = (const float*)d_in[1];
    const float* proj_w = (const float*)d_in[2];
    const float* proj_b = (const float*)d_in[3];
    const float* rpe_w  = (const float*)d_in[4];
    float* out = (float*)d_out;

    char* ws = (char*)d_ws;
    ushort_t* xb   = (ushort_t*)(ws + XB_OFF_B);
    ushort_t* wqkv = (ushort_t*)(ws + WQKV_OFF_B);
    ushort_t* wprj = (ushort_t*)(ws + WPROJ_OFF_B);
    ushort_t* qb   = (ushort_t*)(ws + QB_OFF_B);
    ushort_t* kb   = (ushort_t*)(ws + KB_OFF_B);
    ushort_t* aob  = (ushort_t*)(ws + AOB_OFF_B);
    ushort_t* vt   = (ushort_t*)(ws + VT_OFF_B);
    unsigned char* bucketT = (unsigned char*)(ws + BUCKET_OFF_B);

    const int ncast = (NTOK*C_ + 3*C_*C_ + C_*C_) / 8;
    bucket_kernel<<<dim3((N_*NPAD + 255)/256), 256, 0, stream>>>(bucketT);
    cast_kernel<<<dim3((ncast + 255)/256), 256, 0, stream>>>(x, qkv_w, proj_w, xb, wqkv, wprj);
    qkv_kernel<<<dim3(65, 18), 256, 0, stream>>>(xb, wqkv, qb, kb, vt);
    attn_kernel<<<dim3(96, 17), 256, 0, stream>>>(qb, kb, vt, rpe_w, bucketT, aob);
    proj_kernel<<<dim3(65, 6), 256, 0, stream>>>(aob, wprj, proj_b, out);
}